// Round 6
// baseline (967.125 us; speedup 1.0000x reference)
//
#include <hip/hip_runtime.h>

typedef _Float16 half_t;
typedef half_t half8 __attribute__((ext_vector_type(8)));
typedef half_t half4 __attribute__((ext_vector_type(4)));
typedef float  floatx4 __attribute__((ext_vector_type(4)));

#define NB 2048
#define NT 20
#define CD 512
#define HD 1024
#define VD 2048
#define QD 1024

// Engine: KS=64, 3-buffer rotation, depth-2 prefetch, counted vmcnt (T3/T4).
// Per K-step: waitv<LPT> (own stage(s) landed, stage(s+1) stays in flight) ->
// raw s_barrier (all waves' slices landed) -> issue stage(s+2) -> MFMA.
// This removes the vmcnt(0) drain the old __syncthreads forced every step
// (measured ~2600 cy/step; load latency was fully exposed). Buffer reuse is
// safe: stage(s+2) targets the buffer computed at s-1, and every wave passed
// barrier(s) => finished compute(s-1). Pointer rotation, not runtime indexing
// (rule #20). KS and barrier count unchanged vs the proven round-5 engine.
// LDS linear (global_load_lds dest lane-linear, m104); bank swizzle on the
// pre-swizzled GLOBAL source chunk (m173): chunk ^= row&7.
// Rows counting-sorted by cap_len desc (round 5): active(t) <=> row < cnt[t].

__device__ __forceinline__ float sigmoidf_(float x) { return 1.0f / (1.0f + __expf(-x)); }
__device__ __forceinline__ float tanhf_(float x)    { return 1.0f - 2.0f / (1.0f + __expf(2.0f * x)); }
__device__ __forceinline__ float lrelu_(float x)    { return x > 0.0f ? x : 0.01f * x; }

template <int N> __device__ __forceinline__ void waitv() {
    asm volatile("s_waitcnt vmcnt(%0)" :: "n"(N) : "memory");
}
__device__ __forceinline__ void barrier_() {
    asm volatile("s_barrier" ::: "memory");
}

__device__ __forceinline__ void gload16(const half_t* g, half_t* l) {
    __builtin_amdgcn_global_load_lds(
        (const __attribute__((address_space(1))) void*)g,
        (__attribute__((address_space(3))) void*)l, 16, 0, 0);
}

// XCD-aware remap for a flat role-grid of GX*32 blocks (GX = col-blocks of 32).
__device__ __forceinline__ void remap(int flat, int GX, int& m0, int& c0) {
    const int xcd = flat & 7;
    const int i   = flat >> 3;
    c0 = (xcd * (GX >> 3) + (i >> 5)) * 32;
    m0 = (i & 31) * 64;
}

// Dual-phase GEMM: acc[mapA[g]] += A1[64xK1] @ W1_g^T then
// acc[mapB[g]] += A2[64xK2] @ W2_g^T.  W tiles are BN x K, A is 64 x K.
template <int NG, int BN, int NACC,
          int I0A, int I1A, int I2A, int I0B, int I1B, int I2B>
__device__ __forceinline__ void gemm2(
    const half_t* __restrict__ A1, int lda1, const half_t* __restrict__ W1, long gs1, int S1,
    const half_t* __restrict__ A2, int lda2, const half_t* __restrict__ W2, long gs2, int S2,
    int m0, int c0, half_t* lds, floatx4 (&acc)[NACC][2][BN / 32])
{
    constexpr int ASZ = 64 * 64;
    constexpr int WL  = (NG * BN * 8) / 256;
    constexpr int BUF = ASZ + NG * BN * 64;
    constexpr int LPT = 2 + WL;              // vmem issues per thread per stage
    constexpr int NIN = BN / 32;
    constexpr int map_[3] = {I0A, I1A, I2A};
    constexpr int mapB[3] = {I0B, I1B, I2B};

    const int tid  = threadIdx.x;
    const int lane = tid & 63;
    const int wid  = tid >> 6;
    const int wr   = (wid >> 1) * 32;
    const int wc   = (wid & 1) * (BN / 2);
    const int frow = lane & 15;
    const int cb   = lane >> 4;

    const int srow = tid >> 3;
    const int sq   = ((tid & 7) ^ (srow & 7)) * 8;
    const int sdl  = srow * 64 + (tid & 7) * 8;
    const long aoff1 = (long)(m0 + srow) * lda1 + sq;
    const long aoff2 = (long)(m0 + srow) * lda2 + sq;

    int  wdst[WL];
    long woff1[WL], woff2[WL];
#pragma unroll
    for (int j = 0; j < WL; ++j) {
        const int u   = tid + j * 256;
        const int g   = u / (BN * 8);
        const int idx = u - g * (BN * 8);
        const int row = idx >> 3;
        const int q   = ((idx & 7) ^ (row & 7)) * 8;
        wdst[j]  = ASZ + u * 8;
        woff1[j] = (long)g * gs1 + (long)(c0 + row) * (S1 * 64) + q;
        woff2[j] = (long)g * gs2 + (long)(c0 + row) * (S2 * 64) + q;
    }

    const int S = S1 + S2;
    auto stage = [&](int s, half_t* lb) {
        if (s < S1) {
            const int k0 = s * 64;
            gload16(A1 + aoff1 + k0,             lb + sdl);
            gload16(A1 + aoff1 + 32 * lda1 + k0, lb + 32 * 64 + sdl);
#pragma unroll
            for (int j = 0; j < WL; ++j) gload16(W1 + woff1[j] + k0, lb + wdst[j]);
        } else {
            const int k0 = (s - S1) * 64;
            gload16(A2 + aoff2 + k0,             lb + sdl);
            gload16(A2 + aoff2 + 32 * lda2 + k0, lb + 32 * 64 + sdl);
#pragma unroll
            for (int j = 0; j < WL; ++j) gload16(W2 + woff2[j] + k0, lb + wdst[j]);
        }
    };

    half_t* b0 = lds;
    half_t* b1 = lds + BUF;
    half_t* b2 = lds + 2 * BUF;
    stage(0, b0);
    if (S > 1) stage(1, b1);
    half_t* pc = b0;    // compute buffer
    half_t* pn = b1;    // next compute
    half_t* ps = b2;    // stage destination

    for (int s = 0; s < S; ++s) {
        if (s + 1 < S) waitv<LPT>(); else waitv<0>();
        barrier_();
        if (s + 2 < S) stage(s + 2, ps);
        const half_t* lb = pc;
        const bool pa = (s < S1);
#pragma unroll
        for (int kk = 0; kk < 2; ++kk) {
            half8 af[2];
#pragma unroll
            for (int im = 0; im < 2; ++im) {
                const int r = wr + im * 16 + frow;
                af[im] = *(const half8*)(lb + r * 64 + (((kk * 4 + cb) ^ (r & 7)) * 8));
            }
#pragma unroll
            for (int g = 0; g < NG; ++g) {
#pragma unroll
                for (int in = 0; in < NIN; ++in) {
                    const int r = wc + in * 16 + frow;
                    const half8 bf = *(const half8*)(lb + ASZ + g * (BN * 64) + r * 64 +
                                                     (((kk * 4 + cb) ^ (r & 7)) * 8));
                    const int d = pa ? map_[g] : mapB[g];
#pragma unroll
                    for (int im = 0; im < 2; ++im)
                        acc[d][im][in] = __builtin_amdgcn_mfma_f32_16x16x32_f16(
                            af[im], bf, acc[d][im][in], 0, 0, 0);
                }
            }
        }
        half_t* tp = pc; pc = pn; pn = ps; ps = tp;
    }
    barrier_();   // protect LDS reuse by a following gemm2 call
}

// ---- counting sort of rows by cap_len DESCENDING ----
__global__ void sort_kernel(const int* __restrict__ cap_len,
                            int* __restrict__ perm, int* __restrict__ cnt)
{
    __shared__ int hist[NT];
    __shared__ int off[NT];
    const int tid = threadIdx.x;
    if (tid < NT) hist[tid] = 0;
    __syncthreads();
    for (int i = tid; i < NB; i += 256) atomicAdd(&hist[cap_len[i]], 1);
    __syncthreads();
    if (tid == 0) {
        int run = 0;
        for (int v = NT - 1; v >= 0; --v) { off[v] = run; run += hist[v]; }
        for (int t = 0; t < NT; ++t) cnt[t] = off[t];
        for (int t = NT; t < 32; ++t) cnt[t] = 0;
    }
    __syncthreads();
    for (int i = tid; i < NB; i += 256) {
        const int pos = atomicAdd(&off[cap_len[i]], 1);
        perm[pos] = i;
    }
}

// ---- fused fp32->fp16 conversion; per-row buffers permuted + trimmed ----
struct CvtArgs {
    const float* src[10];
    half_t* dst[10];
    int start[11];
    int rowlen[10];
    const int* perm;
    const int* cnt;
};
__global__ void cvt_all_kernel(CvtArgs a) {
    const int b = blockIdx.x;
    int i = 0;
#pragma unroll
    for (int k = 0; k < 9; ++k) i += (b >= a.start[k + 1]);
    const int idx = ((b - a.start[i]) * 256 + (int)threadIdx.x) * 4;
    long sidx = idx;
    const int rl = a.rowlen[i];
    if (rl) {
        const int row = idx / rl;
        if (row >= a.cnt[0]) return;
        sidx = (long)a.perm[row] * rl + (idx - row * rl);
    }
    float4 f = *(const float4*)(a.src[i] + sidx);
    half4 h = {(half_t)f.x, (half_t)f.y, (half_t)f.z, (half_t)f.w};
    *(half4*)(a.dst[i] + idx) = h;
}

// ---- role bodies (sorted row space; cn = cnt[t] for this role) ----

__device__ __forceinline__ void step1_body(
    int flat,
    const half_t* __restrict__ cap_h,
    const half_t* __restrict__ wih1, const half_t* __restrict__ whh1,
    const float* __restrict__ b_ih1, const float* __restrict__ b_hh1,
    const half_t* __restrict__ h1_src, half_t* __restrict__ h1_dst,
    const float* __restrict__ fvq, const float* __restrict__ caption,
    const int* __restrict__ perm, int cn,
    half_t* __restrict__ att_w, float* __restrict__ alphas, int t, half_t* lds)
{
    int m0, c0; remap(flat, 16, m0, c0);
    if (m0 >= cn) return;
    floatx4 acc[4][2][1];
#pragma unroll
    for (int g = 0; g < 4; ++g) for (int im = 0; im < 2; ++im)
        acc[g][im][0] = (floatx4){0.f, 0.f, 0.f, 0.f};
    gemm2<3, 32, 4, 0, 1, 2, 0, 1, 3>(
        cap_h + t * CD, NT * CD, wih1, (long)CD * CD, CD / 64,
        h1_src, CD, whh1, (long)CD * CD, CD / 64, m0, c0, lds, acc);

    const int lane = threadIdx.x & 63;
    const int wid = threadIdx.x >> 6;
    const int wr = (wid >> 1) * 32, wc = (wid & 1) * 16;
#pragma unroll
    for (int im = 0; im < 2; ++im) {
        const int mb = m0 + wr + im * 16 + (lane >> 4) * 4;
        const int c  = c0 + wc + (lane & 15);
        const float br = b_ih1[c] + b_hh1[c];
        const float bz = b_ih1[CD + c] + b_hh1[CD + c];
        const float bin_ = b_ih1[2 * CD + c];
        const float bhn  = b_hh1[2 * CD + c];
#pragma unroll
        for (int j = 0; j < 4; ++j) {
            const int m = mb + j;
            const float r = sigmoidf_(acc[0][im][0][j] + br);
            const float z = sigmoidf_(acc[1][im][0][j] + bz);
            const float n = tanhf_(acc[2][im][0][j] + bin_ + r * (acc[3][im][0][j] + bhn));
            const float h_old = (float)h1_src[m * CD + c];
            const bool act = m < cn;
            const float h_new = act ? ((1.f - z) * n + z * h_old) : h_old;
            const int orig = perm[m];
            const float x = caption[((long)orig * NT + t) * CD + c];
            const float at = sigmoidf_(h_new * fvq[m * CD + c]) * x;
            h1_dst[m * CD + c] = (half_t)h_new;
            att_w[m * CD + c]  = (half_t)at;
            if (act) alphas[((long)orig * NT + t) * CD + c] = at;
        }
    }
}

__device__ __forceinline__ void step2_body(
    int flat,
    const half_t* __restrict__ att_r,
    const half_t* __restrict__ wih2, const half_t* __restrict__ whh2,
    const float* __restrict__ b_ih2, const float* __restrict__ b_hh2,
    const half_t* __restrict__ h2_src, half_t* __restrict__ h2_dst,
    int cn, int t, half_t* lds)
{
    int m0, c0; remap(flat, 32, m0, c0);
    if (m0 >= cn) return;
    floatx4 acc[4][2][1];
#pragma unroll
    for (int g = 0; g < 4; ++g) for (int im = 0; im < 2; ++im)
        acc[g][im][0] = (floatx4){0.f, 0.f, 0.f, 0.f};
    gemm2<3, 32, 4, 0, 1, 2, 0, 1, 3>(
        att_r, CD, wih2, (long)HD * CD, CD / 64,
        h2_src, HD, whh2, (long)HD * HD, HD / 64, m0, c0, lds, acc);

    const int lane = threadIdx.x & 63;
    const int wid = threadIdx.x >> 6;
    const int wr = (wid >> 1) * 32, wc = (wid & 1) * 16;
#pragma unroll
    for (int im = 0; im < 2; ++im) {
        const int mb = m0 + wr + im * 16 + (lane >> 4) * 4;
        const int c  = c0 + wc + (lane & 15);
        const float br = b_ih2[c] + b_hh2[c];
        const float bz = b_ih2[HD + c] + b_hh2[HD + c];
        const float bin_ = b_ih2[2 * HD + c];
        const float bhn  = b_hh2[2 * HD + c];
#pragma unroll
        for (int j = 0; j < 4; ++j) {
            const int m = mb + j;
            const float r = sigmoidf_(acc[0][im][0][j] + br);
            const float z = sigmoidf_(acc[1][im][0][j] + bz);
            const float n = tanhf_(acc[2][im][0][j] + bin_ + r * (acc[3][im][0][j] + bhn));
            const float h_old = (float)h2_src[m * HD + c];
            const bool act = m < cn;
            h2_dst[m * HD + c] = (half_t)(act ? ((1.f - z) * n + z * h_old) : h_old);
        }
    }
}

__device__ __forceinline__ void step3_body(
    int flat,
    const half_t* __restrict__ h2_cur, const half_t* __restrict__ wfc,
    const int* __restrict__ perm, int cn,
    float* __restrict__ outmax, half_t* lds)
{
    int m0, c0; remap(flat, 32, m0, c0);
    if (m0 >= cn) return;
    floatx4 acc[1][2][1];
#pragma unroll
    for (int im = 0; im < 2; ++im)
        acc[0][im][0] = (floatx4){0.f, 0.f, 0.f, 0.f};
    gemm2<1, 32, 1, 0, 0, 0, 0, 0, 0>(
        h2_cur, HD, wfc, 0, HD / 64,
        h2_cur, HD, wfc, 0, 0, m0, c0, lds, acc);

    const int lane = threadIdx.x & 63;
    const int wid = threadIdx.x >> 6;
    const int wr = (wid >> 1) * 32, wc = (wid & 1) * 16;
#pragma unroll
    for (int im = 0; im < 2; ++im) {
        const int mb = m0 + wr + im * 16 + (lane >> 4) * 4;
        const int c  = c0 + wc + (lane & 15);
#pragma unroll
        for (int j = 0; j < 4; ++j) {
            const int m = mb + j;
            if (m < cn) {
                const int orig = perm[m];
                const float v0 = lrelu_(acc[0][im][0][j]);
                float* p = &outmax[(long)orig * HD + c];
                *p = fmaxf(*p, v0);
            }
        }
    }
}

// ---- step1_0: fvq GEMM + step1(t=0) with h1==0 (gh phase vanishes) ----
__global__ __launch_bounds__(256, 2) void step1_0_kernel(
    const half_t* __restrict__ v_h, const half_t* __restrict__ wv_w,
    const half_t* __restrict__ q_h, const half_t* __restrict__ wq_w,
    const half_t* __restrict__ cap_h, const half_t* __restrict__ wih1,
    const float* __restrict__ b_ih1, const float* __restrict__ b_hh1,
    half_t* __restrict__ h1_dst, float* __restrict__ fvq_out,
    const float* __restrict__ caption, const int* __restrict__ perm,
    const int* __restrict__ cnt,
    half_t* __restrict__ att_w, float* __restrict__ alphas)
{
    __shared__ half_t lds[3 * (64 * 64 + 3 * 32 * 64)];
    const int cn = cnt[0];
    int m0, c0; remap(blockIdx.x, 16, m0, c0);
    if (m0 >= cn) return;

    floatx4 acc1[2][2][1];
#pragma unroll
    for (int g = 0; g < 2; ++g) for (int im = 0; im < 2; ++im)
        acc1[g][im][0] = (floatx4){0.f, 0.f, 0.f, 0.f};
    gemm2<1, 32, 2, 0, 0, 0, 1, 0, 0>(
        v_h, VD, wv_w, 0, VD / 64, q_h, QD, wq_w, 0, QD / 64, m0, c0, lds, acc1);

    floatx4 acc2[3][2][1];
#pragma unroll
    for (int g = 0; g < 3; ++g) for (int im = 0; im < 2; ++im)
        acc2[g][im][0] = (floatx4){0.f, 0.f, 0.f, 0.f};
    gemm2<3, 32, 3, 0, 1, 2, 0, 1, 2>(
        cap_h, NT * CD, wih1, (long)CD * CD, CD / 64,
        cap_h, NT * CD, wih1, (long)CD * CD, 0, m0, c0, lds, acc2);

    const int lane = threadIdx.x & 63;
    const int wid = threadIdx.x >> 6;
    const int wr = (wid >> 1) * 32, wc = (wid & 1) * 16;
#pragma unroll
    for (int im = 0; im < 2; ++im) {
        const int mb = m0 + wr + im * 16 + (lane >> 4) * 4;
        const int c  = c0 + wc + (lane & 15);
        const float br = b_ih1[c] + b_hh1[c];
        const float bz = b_ih1[CD + c] + b_hh1[CD + c];
        const float bin_ = b_ih1[2 * CD + c];
        const float bhn  = b_hh1[2 * CD + c];
#pragma unroll
        for (int j = 0; j < 4; ++j) {
            const int m = mb + j;
            const float fv = lrelu_(acc1[0][im][0][j]) + lrelu_(acc1[1][im][0][j]);
            fvq_out[m * CD + c] = fv;
            const float r = sigmoidf_(acc2[0][im][0][j] + br);
            const float z = sigmoidf_(acc2[1][im][0][j] + bz);
            const float n = tanhf_(acc2[2][im][0][j] + bin_ + r * bhn);
            const bool act = m < cn;
            const float h_new = act ? (1.f - z) * n : 0.f;
            const int orig = perm[m];
            const float x = caption[(long)orig * NT * CD + c];
            const float at = sigmoidf_(h_new * fv) * x;
            h1_dst[m * CD + c] = (half_t)h_new;
            att_w[m * CD + c]  = (half_t)at;
            if (act) alphas[(long)orig * NT * CD + c] = at;
        }
    }
}

// ---- fused321: step2(t) [0,1024) || step1(t+1) [1024,1536) || step3(t-1) [1536,2560) ----
__global__ __launch_bounds__(256, 2) void fused321_kernel(
    const half_t* __restrict__ att0, half_t* __restrict__ att1,
    const half_t* __restrict__ wih2, const half_t* __restrict__ whh2,
    const float* __restrict__ b_ih2, const float* __restrict__ b_hh2,
    const half_t* __restrict__ h2b0, half_t* __restrict__ h2b1,
    const half_t* __restrict__ cap_h,
    const half_t* __restrict__ wih1, const half_t* __restrict__ whh1,
    const float* __restrict__ b_ih1, const float* __restrict__ b_hh1,
    const half_t* __restrict__ h1b0, half_t* __restrict__ h1b1,
    const float* __restrict__ fvq, const float* __restrict__ caption,
    const half_t* __restrict__ wfc,
    const int* __restrict__ perm, const int* __restrict__ cnt,
    float* __restrict__ outmax, float* __restrict__ alphas, int t)
{
    __shared__ half_t lds[3 * (64 * 64 + 3 * 32 * 64)];
    const int par = t & 1;
    const half_t* att_r = par ? att1 : att0;
    half_t*       att_w = par ? (half_t*)att0 : att1;
    const half_t* h2_r  = par ? h2b1 : h2b0;
    half_t*       h2_w  = par ? (half_t*)h2b0 : h2b1;
    const half_t* h1_r  = par ? h1b0 : h1b1;
    half_t*       h1_w  = par ? h1b1 : (half_t*)h1b0;

    const int bx = blockIdx.x;
    if (bx < 1024) {
        if (t < NT)
            step2_body(bx, att_r, wih2, whh2, b_ih2, b_hh2, h2_r, h2_w,
                       cnt[t], t, lds);
    } else if (bx < 1536) {
        if (t < NT - 1)
            step1_body(bx - 1024, cap_h, wih1, whh1, b_ih1, b_hh1,
                       h1_r, h1_w, fvq, caption, perm, cnt[t + 1],
                       att_w, alphas, t + 1, lds);
    } else {
        if (t >= 1)
            step3_body(bx - 1536, h2_r, wfc, perm, cnt[t - 1], outmax, lds);
    }
}

extern "C" void kernel_launch(void* const* d_in, const int* in_sizes, int n_in,
                              void* d_out, int out_size, void* d_ws, size_t ws_size,
                              hipStream_t stream)
{
    (void)in_sizes; (void)n_in; (void)out_size; (void)ws_size;
    const float* v     = (const float*)d_in[0];
    const float* q     = (const float*)d_in[1];
    const float* cap   = (const float*)d_in[2];
    const int*   cap_len = (const int*)d_in[3];
    const float* w_ih1 = (const float*)d_in[4];
    const float* w_hh1 = (const float*)d_in[5];
    const float* b_ih1 = (const float*)d_in[6];
    const float* b_hh1 = (const float*)d_in[7];
    const float* w_ih2 = (const float*)d_in[8];
    const float* w_hh2 = (const float*)d_in[9];
    const float* b_ih2 = (const float*)d_in[10];
    const float* b_hh2 = (const float*)d_in[11];
    const float* Wv    = (const float*)d_in[12];
    const float* Wq    = (const float*)d_in[13];
    const float* Wfc   = (const float*)d_in[14];

    float* out_max = (float*)d_out;                    // [NB, HD]
    float* alphas  = (float*)d_out + (size_t)NB * HD;  // [NB, NT, CD]

    half_t* p = (half_t*)d_ws;
    half_t* v_h    = p; p += (size_t)NB * VD;
    half_t* q_h    = p; p += (size_t)NB * QD;
    half_t* cap_h  = p; p += (size_t)NB * NT * CD;
    half_t* wih1_h = p; p += 3 * CD * CD;
    half_t* whh1_h = p; p += 3 * CD * CD;
    half_t* wih2_h = p; p += 3 * HD * CD;
    half_t* whh2_h = p; p += 3 * HD * HD;
    half_t* wfc_h  = p; p += HD * HD;
    half_t* wv_h   = p; p += CD * VD;
    half_t* wq_h   = p; p += CD * QD;
    half_t* h1b0   = p; p += (size_t)NB * CD;
    half_t* h1b1   = p; p += (size_t)NB * CD;
    half_t* h2b0   = p; p += (size_t)NB * HD;
    half_t* h2b1   = p; p += (size_t)NB * HD;
    half_t* att0   = p; p += (size_t)NB * CD;
    half_t* att1   = p; p += (size_t)NB * CD;
    float* fvq = (float*)p; p += (size_t)NB * CD * 2;
    int* perm = (int*)p;
    int* cnt  = perm + NB;

    hipMemsetAsync(out_max, 0, (size_t)NB * HD * sizeof(float), stream);
    hipMemsetAsync(alphas, 0, (size_t)NB * NT * CD * sizeof(float), stream);
    hipMemsetAsync(h2b0, 0, (size_t)NB * HD * sizeof(half_t), stream);

    sort_kernel<<<1, 256, 0, stream>>>(cap_len, perm, cnt);

    CvtArgs ca;
    const float* srcs[10] = {v, q, cap, w_ih1, w_hh1, w_ih2, w_hh2, Wfc, Wv, Wq};
    half_t* dsts[10] = {v_h, q_h, cap_h, wih1_h, whh1_h, wih2_h, whh2_h, wfc_h, wv_h, wq_h};
    const int ns[10] = {NB * VD, NB * QD, NB * NT * CD, 3 * CD * CD, 3 * CD * CD,
                        3 * HD * CD, 3 * HD * HD, HD * HD, CD * VD, CD * QD};
    const int rls[10] = {VD, QD, NT * CD, 0, 0, 0, 0, 0, 0, 0};
    int acc_blk = 0;
    for (int i = 0; i < 10; ++i) {
        ca.src[i] = srcs[i]; ca.dst[i] = dsts[i]; ca.rowlen[i] = rls[i];
        ca.start[i] = acc_blk; acc_blk += ns[i] / 1024;
    }
    ca.start[10] = acc_blk;
    ca.perm = perm; ca.cnt = cnt;
    cvt_all_kernel<<<acc_blk, 256, 0, stream>>>(ca);

    // t=0: fvq + step1(0) fused (h1==0). Writes h1b1, att0, alphas[:,0,:], fvq.
    step1_0_kernel<<<512, 256, 0, stream>>>(
        v_h, wv_h, q_h, wq_h, cap_h, wih1_h, b_ih1, b_hh1,
        h1b1, fvq, cap, perm, cnt, att0, alphas);

    // t = 0..20: step2(t) || step1(t+1) || step3(t-1), guards at the edges.
    for (int t = 0; t <= NT; ++t) {
        fused321_kernel<<<2560, 256, 0, stream>>>(
            att0, att1, wih2_h, whh2_h, b_ih2, b_hh2, h2b0, h2b1,
            cap_h, wih1_h, whh1_h, b_ih1, b_hh1, h1b0, h1b1,
            fvq, cap, wfc_h, perm, cnt, out_max, alphas, t);
    }
}